// Round 3
// baseline (719.730 us; speedup 1.0000x reference)
//
#include <hip/hip_runtime.h>

typedef unsigned short u16;
typedef unsigned int   u32;
typedef short short8 __attribute__((ext_vector_type(8)));
typedef float f32x4 __attribute__((ext_vector_type(4)));
typedef _Float16 f16;
typedef f16 f16x2 __attribute__((ext_vector_type(2)));
typedef f16 f16x8 __attribute__((ext_vector_type(8)));

#define B_ 8
#define T_ 1024
#define E_ 1024
#define H_ 16
#define D_ 64
#define BH_ 128
#define NPROJ 4096
#define NATTN 2048
#define ATTN0 (BH_ + NPROJ)

__device__ __forceinline__ float fexp2(float x){
#if __has_builtin(__builtin_amdgcn_exp2f)
    return __builtin_amdgcn_exp2f(x);
#else
    return exp2f(x);
#endif
}

// tanh via exp2: tanh(x) = 1 - 2/(exp(2x)+1); clamp in log2 domain.
__device__ __forceinline__ float ftanh(float x){
    float xl = fminf(23.0f, fmaxf(-23.0f, x * 2.885390081777927f)); // 2*log2(e)*x
    float e2 = fexp2(xl);
    return 1.0f - 2.0f * __builtin_amdgcn_rcpf(e2 + 1.0f);
}

__device__ __forceinline__ u16 f2h(float x){
    union { f16 h; u16 u; } v; v.h = (f16)x; return v.u;
}

__device__ __forceinline__ float h2f(u16 u){
    union { u16 u; f16 h; } v; v.u = u; return (float)v.h;
}

// ---------------------------------------------------------------------------
// Cross-XCD sync primitives. Producers publish via write-through (agent-scope
// relaxed atomic) data stores + vmcnt drain + relaxed flag store; consumers
// acquire-load the flag (emits cache-inv killing stale L2 lines, incl. lines
// cached by a PREVIOUS bench run under graph replay).
// ---------------------------------------------------------------------------
__device__ __forceinline__ int ld_acq(int* p){
    return __hip_atomic_load(p, __ATOMIC_ACQUIRE, __HIP_MEMORY_SCOPE_AGENT);
}
// lane-0-per-wave spin; whole wave proceeds when satisfied (lockstep).
// Returns the last observed value (broadcast). Bounded to avoid hangs.
__device__ __forceinline__ int wave_wait_ge(int* p, int need, int lane){
    int v = 0;
    if (lane == 0) {
        v = ld_acq(p);
        int g = 0;
        while (v < need) {
            __builtin_amdgcn_s_sleep(64);
            v = ld_acq(p);
            if (++g > (1 << 19)) break;   // ~1s cap: fail loud, don't hang
        }
    }
    return __builtin_amdgcn_readfirstlane(v);
}

// ---------------------------------------------------------------------------
// RNN broadcast network, all in the VALU pipe. The pair (h[l], h[l^1]) is the
// carried state: it feeds both the DPP all-gather AND the u32 data store.
// Permutation + swap conventions self-calibrated (lane-id payload).
// ---------------------------------------------------------------------------
#define DPPC(s, ctrl) ((u32)__builtin_amdgcn_update_dpp(0, (int)(s), (ctrl), 0xF, 0xF, false))

struct G8 { u32 r0, r1, r2, r3, r4, r5, r6, r7; };

__device__ __forceinline__ u32 mkpair(u32 hb){
    return hb | (DPPC(hb, 0xB1) << 16);       // (h[l], h[l^1])
}

__device__ __forceinline__ G8 gather_from_pair(u32 r0){
    G8 g;
    g.r0 = r0;
    g.r1 = DPPC(r0,   0x4E);   // quad_perm [2,3,0,1] (lane^2)
    g.r2 = DPPC(r0,   0x124);  // row_ror:4
    g.r3 = DPPC(g.r1, 0x124);
    g.r4 = DPPC(r0,   0x128);  // row_ror:8
    g.r5 = DPPC(g.r1, 0x128);
    g.r6 = DPPC(g.r2, 0x128);  // ror:12 composite
    g.r7 = DPPC(g.r3, 0x128);
    return g;
}

__device__ __forceinline__ float fd(u32 w, u32 x, float acc){
    return __builtin_amdgcn_fdot2(__builtin_bit_cast(f16x2, w),
                                  __builtin_bit_cast(f16x2, x), acc, false);
}

__device__ __forceinline__ float perm16x(float v, bool sel){
    u32 a = __builtin_bit_cast(u32, v), b = a;
    asm volatile("v_permlane16_swap_b32 %0, %1" : "+v"(a), "+v"(b));
    return __builtin_bit_cast(float, sel ? a : b);
}
__device__ __forceinline__ float perm32x(float v, bool sel){
    u32 a = __builtin_bit_cast(u32, v), b = a;
    asm volatile("v_permlane32_swap_b32 %0, %1" : "+v"(a), "+v"(b));
    return __builtin_bit_cast(float, sel ? a : b);
}

// One recurrence step; pair in, pair out.
template<bool USEPERM>
__device__ __forceinline__ u32 rnn_step(u32 pair, const u32 (&W)[4][8], float cbias,
                                        bool q1f, bool q2f, bool sel16, bool sel32)
{
    G8 g = gather_from_pair(pair);
    float p0 = fd(W[0][0], g.r0, 0.f);
    float p1 = fd(W[1][0], g.r0, 0.f);
    float p2 = fd(W[2][0], g.r0, 0.f);
    float p3 = fd(W[3][0], g.r0, 0.f);
    p0 = fd(W[0][1], g.r1, p0); p1 = fd(W[1][1], g.r1, p1);
    p2 = fd(W[2][1], g.r1, p2); p3 = fd(W[3][1], g.r1, p3);
    p0 = fd(W[0][2], g.r2, p0); p1 = fd(W[1][2], g.r2, p1);
    p2 = fd(W[2][2], g.r2, p2); p3 = fd(W[3][2], g.r2, p3);
    p0 = fd(W[0][3], g.r3, p0); p1 = fd(W[1][3], g.r3, p1);
    p2 = fd(W[2][3], g.r3, p2); p3 = fd(W[3][3], g.r3, p3);
    p0 = fd(W[0][4], g.r4, p0); p1 = fd(W[1][4], g.r4, p1);
    p2 = fd(W[2][4], g.r4, p2); p3 = fd(W[3][4], g.r4, p3);
    p0 = fd(W[0][5], g.r5, p0); p1 = fd(W[1][5], g.r5, p1);
    p2 = fd(W[2][5], g.r5, p2); p3 = fd(W[3][5], g.r5, p3);
    p0 = fd(W[0][6], g.r6, p0); p1 = fd(W[1][6], g.r6, p1);
    p2 = fd(W[2][6], g.r6, p2); p3 = fd(W[3][6], g.r6, p3);
    p0 = fd(W[0][7], g.r7, p0); p1 = fd(W[1][7], g.r7, p1);
    p2 = fd(W[2][7], g.r7, p2); p3 = fd(W[3][7], g.r7, p3);

    // reduce-scatter bit4: keep rows with (i&1)==q1, send the others
    float A0 = q1f ? p1 : p0, S0 = q1f ? p0 : p1;
    float A1 = q1f ? p3 : p2, S1 = q1f ? p2 : p3;
    if (USEPERM) {
        A0 += perm16x(S0, sel16);
        A1 += perm16x(S1, sel16);
    } else {
        A0 += __shfl_xor(S0, 16);
        A1 += __shfl_xor(S1, 16);
    }
    // reduce-scatter bit5: keep row l
    float K  = q2f ? A1 : A0;
    float SS = q2f ? A0 : A1;
    float recv = USEPERM ? perm32x(SS, sel32) : __shfl_xor(SS, 32);
    float yv = K + recv;
    return mkpair((u32)f2h(ftanh(yv + cbias)));
}

#define MFMA16(a, b, c) __builtin_amdgcn_mfma_f32_16x16x32_f16(a, b, c, 0, 0, 0)

// ---------------------------------------------------------------------------
// ONE fused kernel, three roles by blockIdx.x (dispatch is in-order, so
// producers always precede consumers into the machine):
//   [0,128):       RNN chains, publish 64-row tiles via prog[bh]
//   [128,4224):    q/v projection, publish via proj_done counter
//   [4224,6272):   flash attention, streams k-tiles behind the RNN frontier
// This overlaps the ~180us attention phase with the ~190us serial RNN phase.
// ---------------------------------------------------------------------------
__global__ __launch_bounds__(256, 1) void salt_fused_kernel(
    const float* __restrict__ src, const float* __restrict__ tgt,
    const float* __restrict__ Wq,  const float* __restrict__ Wv,
    const float* __restrict__ Wih, const float* __restrict__ Whh,
    const float* __restrict__ bih, const float* __restrict__ bhh,
    const float* __restrict__ Wo,  float* __restrict__ out,
    u16* __restrict__ qh, u16* __restrict__ vh, u16* __restrict__ nwh,
    int* __restrict__ flags)
{
    int bid = blockIdx.x;
    if (bid < BH_) {
        // ================= RNN role: single wave =================
        if (threadIdx.x >= 64) return;
        __builtin_amdgcn_s_setprio(3);
        const int b = bid >> 4, h = bid & 15;
        const int l = threadIdx.x;
        const bool q1f = (l & 16) != 0;
        const bool q2f = (l & 32) != 0;

        // gather-network calibration (lane-id payload, exact in f16)
        G8 cg = gather_from_pair(mkpair((u32)f2h((float)l)));
        int kidx[16];
        kidx[0]  = (int)h2f((u16)(cg.r0 & 0xFFFF)); kidx[1]  = (int)h2f((u16)(cg.r0 >> 16));
        kidx[2]  = (int)h2f((u16)(cg.r1 & 0xFFFF)); kidx[3]  = (int)h2f((u16)(cg.r1 >> 16));
        kidx[4]  = (int)h2f((u16)(cg.r2 & 0xFFFF)); kidx[5]  = (int)h2f((u16)(cg.r2 >> 16));
        kidx[6]  = (int)h2f((u16)(cg.r3 & 0xFFFF)); kidx[7]  = (int)h2f((u16)(cg.r3 >> 16));
        kidx[8]  = (int)h2f((u16)(cg.r4 & 0xFFFF)); kidx[9]  = (int)h2f((u16)(cg.r4 >> 16));
        kidx[10] = (int)h2f((u16)(cg.r5 & 0xFFFF)); kidx[11] = (int)h2f((u16)(cg.r5 >> 16));
        kidx[12] = (int)h2f((u16)(cg.r6 & 0xFFFF)); kidx[13] = (int)h2f((u16)(cg.r6 >> 16));
        kidx[14] = (int)h2f((u16)(cg.r7 & 0xFFFF)); kidx[15] = (int)h2f((u16)(cg.r7 >> 16));

        // permlane swap calibration (which output holds lane^16 / lane^32)
        u32 sx = (u32)l, sy = (u32)l;
        asm volatile("v_permlane16_swap_b32 %0, %1" : "+v"(sx), "+v"(sy));
        const bool sel16 = (sx == (u32)(l ^ 16));
        const bool ok16  = sel16 || (sy == (u32)(l ^ 16));
        u32 tx = (u32)l, ty = (u32)l;
        asm volatile("v_permlane32_swap_b32 %0, %1" : "+v"(tx), "+v"(ty));
        const bool sel32 = (tx == (u32)(l ^ 32));
        const bool ok32  = sel32 || (ty == (u32)(l ^ 32));

        // weights: rows (l&15)+16i, columns gathered by kidx, packed f16x2
        const float* WI = Wih + (size_t)h * D_ * D_;
        const float* WH = Whh + (size_t)h * D_ * D_;
        float cbias = bih[h * D_ + l] + bhh[h * D_ + l];
        u32 wm[4][8], wn[4][8];
        #pragma unroll
        for (int i = 0; i < 4; ++i) {
            const float* wiR = WI + (size_t)((l & 15) + 16 * i) * D_;
            const float* whR = WH + (size_t)((l & 15) + 16 * i) * D_;
            #pragma unroll
            for (int j = 0; j < 8; ++j) {
                int k0 = kidx[2 * j], k1 = kidx[2 * j + 1];
                float wI0 = wiR[k0], wI1 = wiR[k1];
                float wH0 = whR[k0], wH1 = whR[k1];
                wn[i][j] = (u32)f2h(wI0)       | ((u32)f2h(wI1)       << 16);
                wm[i][j] = (u32)f2h(wI0 + wH0) | ((u32)f2h(wI1 + wH1) << 16);
            }
        }
        #pragma unroll
        for (int i = 0; i < 4; ++i)
            #pragma unroll
            for (int j = 0; j < 8; ++j)
                asm volatile("" : "+v"(wm[i][j]));
        asm volatile("" : "+v"(cbias));

        // data stores: even lanes store the (h[l],h[l+1]) pair as one u32,
        // agent-scope relaxed atomic => write-through (no dirty L2, no wbl2
        // needed on the publish path).
        u32* nw32 = (u32*)(nwh + (size_t)bid * T_ * D_);
        const bool evenl = (l & 1) == 0;
        const int  col2  = l >> 1;
        u32 pair = mkpair((u32)f2h(tgt[(size_t)b * T_ * E_ + h * D_ + l]));  // k0

        if (__all(ok16 && ok32)) {
            pair = rnn_step<true>(pair, wn, cbias, q1f, q2f, sel16, sel32);   // h1
            if (evenl)
                __hip_atomic_store(nw32 + col2, pair, __ATOMIC_RELAXED, __HIP_MEMORY_SCOPE_AGENT);
            int trow = 1;
            for (int k = 0; k < 16; ++k) {
                const int tend = (k + 1) * 64;
                #pragma unroll 1
                for (; trow < tend; ++trow) {
                    pair = rnn_step<true>(pair, wm, cbias, q1f, q2f, sel16, sel32);
                    if (evenl)
                        __hip_atomic_store(nw32 + trow * 32 + col2, pair,
                                           __ATOMIC_RELAXED, __HIP_MEMORY_SCOPE_AGENT);
                }
                asm volatile("s_waitcnt vmcnt(0)" ::: "memory");
                if (l == 0)
                    __hip_atomic_store(&flags[bid], k + 1,
                                       __ATOMIC_RELAXED, __HIP_MEMORY_SCOPE_AGENT);
            }
        } else {
            // semantics fallback: shuffle-based exchange (slower, correct)
            pair = rnn_step<false>(pair, wn, cbias, q1f, q2f, sel16, sel32);
            if (evenl)
                __hip_atomic_store(nw32 + col2, pair, __ATOMIC_RELAXED, __HIP_MEMORY_SCOPE_AGENT);
            int trow = 1;
            for (int k = 0; k < 16; ++k) {
                const int tend = (k + 1) * 64;
                #pragma unroll 1
                for (; trow < tend; ++trow) {
                    pair = rnn_step<false>(pair, wm, cbias, q1f, q2f, sel16, sel32);
                    if (evenl)
                        __hip_atomic_store(nw32 + trow * 32 + col2, pair,
                                           __ATOMIC_RELAXED, __HIP_MEMORY_SCOPE_AGENT);
                }
                asm volatile("s_waitcnt vmcnt(0)" ::: "memory");
                if (l == 0)
                    __hip_atomic_store(&flags[bid], k + 1,
                                       __ATOMIC_RELAXED, __HIP_MEMORY_SCOPE_AGENT);
            }
        }
    } else if (bid < ATTN0) {
        // ================= projection role =================
        int pb   = bid - BH_;          // 0 .. 4095
        int bh   = pb >> 5;            // (b*16+h)
        int tile = pb & 31;            // 32 t-rows per block
        int b = bh >> 4, h = bh & 15;
        int e  = threadIdx.x & 63;
        int tg = threadIdx.x >> 6;
        int t0 = tile * 32 + tg * 8;

        const float* wq = Wq + (size_t)h * D_ * D_ + e;  // column e, stride 64
        const float* wv = Wv + (size_t)h * D_ * D_ + e;
        const float* s0 = src + ((size_t)b * T_ + t0) * E_ + h * D_;
        const float* g0 = tgt + ((size_t)b * T_ + t0) * E_ + h * D_;

        float aq[8] = {0,0,0,0,0,0,0,0};
        float av[8] = {0,0,0,0,0,0,0,0};
        #pragma unroll 4
        for (int d4 = 0; d4 < 16; ++d4) {
            float q0 = wq[(4*d4+0)*64], q1 = wq[(4*d4+1)*64],
                  q2 = wq[(4*d4+2)*64], q3 = wq[(4*d4+3)*64];
            float v0 = wv[(4*d4+0)*64], v1 = wv[(4*d4+1)*64],
                  v2 = wv[(4*d4+2)*64], v3 = wv[(4*d4+3)*64];
            #pragma unroll
            for (int j = 0; j < 8; ++j) {
                float4 x = *(const float4*)(s0 + (size_t)j * E_ + 4*d4);
                float4 y = *(const float4*)(g0 + (size_t)j * E_ + 4*d4);
                aq[j] += x.x*q0 + x.y*q1 + x.z*q2 + x.w*q3;
                av[j] += y.x*v0 + y.y*v1 + y.z*v2 + y.w*v3;
            }
        }
        // q: [bh][t][e], coalesced u16 rows; fold 1/256 score scale into q
        u16* qp = qh + ((size_t)bh * T_ + t0) * D_ + e;
        #pragma unroll
        for (int j = 0; j < 8; ++j) qp[(size_t)j * D_] = f2h(aq[j] * (1.0f/256.0f));
        // v: TRANSPOSED [bh][d=e][t], one b128 per thread
        f16x8 vv;
        #pragma unroll
        for (int j = 0; j < 8; ++j) vv[j] = (f16)av[j];
        *(f16x8*)(vh + ((size_t)bh * D_ + e) * T_ + t0) = vv;

        // publish: all 4 waves' stores drained by the barrier's vmcnt(0);
        // the RELEASE RMW writes back this XCD's dirty lines (qh/vh).
        __syncthreads();
        if (threadIdx.x == 0)
            __hip_atomic_fetch_add(&flags[BH_], 1,
                                   __ATOMIC_RELEASE, __HIP_MEMORY_SCOPE_AGENT);
    } else {
        // ================= attention role =================
        __shared__ __align__(16) u16 Klds[64 * 64];     // keys; later Wo^T
        __shared__ __align__(16) u16 Vlds[64 * 64];     // V^T: row=d, col=key
        __shared__ __align__(16) u16 Plds[4][16 * 64];  // per-wave P / O relayout

        const int ab   = bid - ATTN0;
        const int tid  = threadIdx.x;
        const int lane = tid & 63;
        const int w    = tid >> 6;
        const int l15  = lane & 15;
        const int quad = lane >> 4;
        const int sw   = lane & 7;
        const int bh   = ab >> 4;
        const int qt   = ab & 15;

        const size_t base  = (size_t)bh * T_ * D_;
        const size_t vbase = (size_t)bh * D_ * T_;

        // wait for ALL projection blocks (publishes qh + vh), per wave
        wave_wait_ge(&flags[BH_], NPROJ, lane);

        f16x8 aq0, aq1;
        {
            int qrow = qt * 64 + w * 16 + l15;
            const f16x8* qp = (const f16x8*)(qh + base + (size_t)qrow * 64 + quad * 8);
            aq0 = qp[0];
            aq1 = qp[4];
        }

        f32x4 oacc[4];
        #pragma unroll
        for (int i = 0; i < 4; ++i) oacc[i] = (f32x4){0.f, 0.f, 0.f, 0.f};
        float lrun[4] = {0.f, 0.f, 0.f, 0.f};

        u16* Pw = Plds[w];
        int seen = 0;   // monotone cached view of prog[bh]

        #pragma unroll 1
        for (int kt = 0; kt < 16; ++kt) {
            // ---- stream behind the RNN frontier ----
            if (seen < kt + 1)
                seen = wave_wait_ge(&flags[bh], kt + 1, lane);

            // ---- stage K rows + V^T rows, both vectorized b128, swizzled ----
            #pragma unroll
            for (int i = 0; i < 2; ++i) {
                int ch = tid + 256 * i;          // 512 chunks of 8 u16
                int r = ch >> 3, cc = ch & 7;
                short8 kval = *(const short8*)(nwh + base + (size_t)(kt * 64 + r) * 64 + cc * 8);
                *(short8*)&Klds[r * 64 + ((cc ^ (r & 7)) * 8)] = kval;
                short8 vval = *(const short8*)(vh + vbase + (size_t)r * T_ + kt * 64 + cc * 8);
                *(short8*)&Vlds[r * 64 + ((cc ^ (r & 7)) * 8)] = vval;
            }
            __syncthreads();

            // ---- S = Q K^T ----
            f32x4 sacc[4];
            #pragma unroll
            for (int u = 0; u < 4; ++u) {
                sacc[u] = (f32x4){0.f, 0.f, 0.f, 0.f};
                int row = 16 * u + l15;
                f16x8 bk0 = *(const f16x8*)&Klds[row * 64 + (((quad + 0) ^ sw) * 8)];
                f16x8 bk1 = *(const f16x8*)&Klds[row * 64 + (((quad + 4) ^ sw) * 8)];
                sacc[u] = MFMA16(aq0, bk0, sacc[u]);
                sacc[u] = MFMA16(aq1, bk1, sacc[u]);
            }

            // ---- softmax accumulation (no max: shift-invariant, |s| tiny) ----
            float pr[4][4];
            #pragma unroll
            for (int r = 0; r < 4; ++r) {
                float rs = 0.f;
                #pragma unroll
                for (int u = 0; u < 4; ++u) {
                    float pv = __expf(sacc[u][r]);
                    pr[u][r] = pv;
                    rs += pv;
                }
                #pragma unroll
                for (int off = 1; off < 16; off <<= 1)
                    rs += __shfl_xor(rs, off, 16);
                lrun[r] += rs;
            }

            // ---- P -> per-wave LDS (C-layout -> A-fragment layout) ----
            #pragma unroll
            for (int u = 0; u < 4; ++u) {
                int col = 16 * u + l15;
                #pragma unroll
                for (int r = 0; r < 4; ++r) {
                    int row = quad * 4 + r;
                    Pw[row * 64 + (((col >> 3) ^ (row & 7)) * 8) + (col & 7)] = f2h(pr[u][r]);
                }
            }

            // ---- O += P V ----
            #pragma unroll
            for (int kc = 0; kc < 2; ++kc) {
                f16x8 ap = *(const f16x8*)&Pw[l15 * 64 + (((quad + 4 * kc) ^ sw) * 8)];
                #pragma unroll
                for (int nt = 0; nt < 4; ++nt) {
                    int drow = 16 * nt + l15;
                    f16x8 bv = *(const f16x8*)&Vlds[drow * 64 + (((quad + 4 * kc) ^ sw) * 8)];
                    oacc[nt] = MFMA16(ap, bv, oacc[nt]);
                }
            }
            __syncthreads();
        }

        // ---- fused output projection: out_tile = (O/l) * Wo[h] ----
        const int b  = bh >> 4, hh = bh & 15;
        {
            const float* wo = Wo + (size_t)hh * D_ * D_;
            #pragma unroll
            for (int i = 0; i < 2; ++i) {
                int ch = tid + 256 * i;          // e = ch>>3, dc = ch&7
                int e = ch >> 3, dc = ch & 7;
                short8 vch;
                #pragma unroll
                for (int j = 0; j < 8; ++j)
                    vch[j] = (short)f2h(wo[(size_t)(dc * 8 + j) * D_ + e]);
                *(short8*)&Klds[e * 64 + ((dc ^ (e & 7)) * 8)] = vch;
            }
        }
        #pragma unroll
        for (int nt = 0; nt < 4; ++nt) {
            int col = 16 * nt + l15;             // d
            #pragma unroll
            for (int r = 0; r < 4; ++r) {
                int row = quad * 4 + r;          // q
                Pw[row * 64 + (((col >> 3) ^ (row & 7)) * 8) + (col & 7)] =
                    f2h(oacc[nt][r] / lrun[r]);
            }
        }
        __syncthreads();    // Wo^T staging visible to all waves

        f16x8 ao0 = *(const f16x8*)&Pw[l15 * 64 + (((quad + 0) ^ sw) * 8)];
        f16x8 ao1 = *(const f16x8*)&Pw[l15 * 64 + (((quad + 4) ^ sw) * 8)];
        f32x4 oo[4];
        #pragma unroll
        for (int nt = 0; nt < 4; ++nt) {
            oo[nt] = (f32x4){0.f, 0.f, 0.f, 0.f};
            int erow = 16 * nt + l15;
            f16x8 b0 = *(const f16x8*)&Klds[erow * 64 + (((quad + 0) ^ (erow & 7)) * 8)];
            f16x8 b1 = *(const f16x8*)&Klds[erow * 64 + (((quad + 4) ^ (erow & 7)) * 8)];
            oo[nt] = MFMA16(ao0, b0, oo[nt]);
            oo[nt] = MFMA16(ao1, b1, oo[nt]);
        }
        #pragma unroll
        for (int nt = 0; nt < 4; ++nt) {
            #pragma unroll
            for (int r = 0; r < 4; ++r) {
                int qg = qt * 64 + w * 16 + quad * 4 + r;
                int e  = 16 * nt + l15;
                out[((size_t)b * T_ + qg) * E_ + hh * D_ + e] = oo[nt][r];
            }
        }
    }
}

// ---------------------------------------------------------------------------
extern "C" void kernel_launch(void* const* d_in, const int* in_sizes, int n_in,
                              void* d_out, int out_size, void* d_ws, size_t ws_size,
                              hipStream_t stream)
{
    const float* src = (const float*)d_in[0];
    const float* tgt = (const float*)d_in[1];
    const float* Wq  = (const float*)d_in[2];
    const float* Wv  = (const float*)d_in[3];
    const float* Wo  = (const float*)d_in[4];
    const float* Wih = (const float*)d_in[5];
    const float* Whh = (const float*)d_in[6];
    const float* bih = (const float*)d_in[7];
    const float* bhh = (const float*)d_in[8];
    float* out = (float*)d_out;

    char* ws = (char*)d_ws;
    u16* qh  = (u16*)(ws);                             // [bh][t][d] 16 MB
    u16* vh  = (u16*)(ws + (size_t)16 * 1024 * 1024);  // V^T [bh][d][t] 16 MB
    u16* nwh = (u16*)(ws + (size_t)32 * 1024 * 1024);  // [bh][t][d] 16 MB
    int* flags = (int*)(ws + (size_t)48 * 1024 * 1024); // prog[128] + proj_done

    (void)in_sizes; (void)n_in; (void)out_size; (void)ws_size;

    hipMemsetAsync(flags, 0, 4096, stream);
    salt_fused_kernel<<<dim3(BH_ + NPROJ + NATTN), 256, 0, stream>>>(
        src, tgt, Wq, Wv, Wih, Whh, bih, bhh, Wo, out, qh, vh, nwh, flags);
}

// Round 5
// 374.489 us; speedup vs baseline: 1.9219x; 1.9219x over previous
//
#include <hip/hip_runtime.h>

typedef unsigned short u16;
typedef short short8 __attribute__((ext_vector_type(8)));
typedef float f32x4 __attribute__((ext_vector_type(4)));
typedef _Float16 f16;
typedef f16 f16x2 __attribute__((ext_vector_type(2)));
typedef f16 f16x8 __attribute__((ext_vector_type(8)));

#define B_ 8
#define T_ 1024
#define E_ 1024
#define H_ 16
#define D_ 64
#define BH_ 128

__device__ __forceinline__ float ftanh(float x){
    x = fminf(8.0f, fmaxf(-8.0f, x));
    float e2 = __expf(2.0f * x);
    return 1.0f - 2.0f * __builtin_amdgcn_rcpf(e2 + 1.0f);
}

__device__ __forceinline__ u16 f2h(float x){
    union { f16 h; u16 u; } v; v.h = (f16)x; return v.u;
}

__device__ __forceinline__ float dot8(f16x8 a, f16x8 b, float acc){
#if __has_builtin(__builtin_amdgcn_fdot2)
    f16x2 a0 = {a[0],a[1]}, a1 = {a[2],a[3]}, a2 = {a[4],a[5]}, a3 = {a[6],a[7]};
    f16x2 b0 = {b[0],b[1]}, b1 = {b[2],b[3]}, b2 = {b[4],b[5]}, b3 = {b[6],b[7]};
    acc = __builtin_amdgcn_fdot2(a0, b0, acc, false);
    acc = __builtin_amdgcn_fdot2(a1, b1, acc, false);
    acc = __builtin_amdgcn_fdot2(a2, b2, acc, false);
    acc = __builtin_amdgcn_fdot2(a3, b3, acc, false);
#else
    #pragma unroll
    for (int i = 0; i < 8; ++i) acc += (float)a[i] * (float)b[i];
#endif
    return acc;
}

__device__ __forceinline__ f16x8 pack8(f32x4 a, f32x4 b){
    f16x8 r;
    r[0]=(f16)a[0]; r[1]=(f16)a[1]; r[2]=(f16)a[2]; r[3]=(f16)a[3];
    r[4]=(f16)b[0]; r[5]=(f16)b[1]; r[6]=(f16)b[2]; r[7]=(f16)b[3];
    return r;
}

// Opaque register pin: keeps recurrent weights VGPR-resident across the loop.
#define PIN8(x) do { f32x4 _t = __builtin_bit_cast(f32x4, x); \
                     asm volatile("" : "+v"(_t));             \
                     x = __builtin_bit_cast(f16x8, _t); } while (0)

// ---------------------------------------------------------------------------
// Kernel 1: fused RNN (blocks 0..127) + q/v projection (blocks 128..).
// VERBATIM round-0 version (measured 215us RNN): LDS h-broadcast beat the
// DPP rewrite and setprio; fused cross-role streaming tripled HBM fetch.
// ---------------------------------------------------------------------------
__global__ __launch_bounds__(256, 1) void proj_rnn_kernel(
    const float* __restrict__ src, const float* __restrict__ tgt,
    const float* __restrict__ Wq,  const float* __restrict__ Wv,
    const float* __restrict__ Wih, const float* __restrict__ Whh,
    const float* __restrict__ bih, const float* __restrict__ bhh,
    u16* __restrict__ qh, u16* __restrict__ vh, u16* __restrict__ nwh)
{
    int bid = blockIdx.x;
    if (bid < BH_) {
        if (threadIdx.x >= 64) return;
        __shared__ __align__(16) u16 hl[D_];
        const int b = bid >> 4, h = bid & 15;
        const int e = threadIdx.x;

        const f32x4* wi4 = (const f32x4*)(Wih + ((size_t)h * D_ + e) * D_);
        const f32x4* wh4 = (const f32x4*)(Whh + ((size_t)h * D_ + e) * D_);
        float c = bih[h * D_ + e] + bhh[h * D_ + e];
        asm volatile("" : "+v"(c));

        f16x8 n0 = pack8(wi4[0],  wi4[1]),  n1 = pack8(wi4[2],  wi4[3]);
        f16x8 n2 = pack8(wi4[4],  wi4[5]),  n3 = pack8(wi4[6],  wi4[7]);
        f16x8 n4 = pack8(wi4[8],  wi4[9]),  n5 = pack8(wi4[10], wi4[11]);
        f16x8 n6 = pack8(wi4[12], wi4[13]), n7 = pack8(wi4[14], wi4[15]);
        f16x8 m0 = pack8(wi4[0]+wh4[0],   wi4[1]+wh4[1]);
        f16x8 m1 = pack8(wi4[2]+wh4[2],   wi4[3]+wh4[3]);
        f16x8 m2 = pack8(wi4[4]+wh4[4],   wi4[5]+wh4[5]);
        f16x8 m3 = pack8(wi4[6]+wh4[6],   wi4[7]+wh4[7]);
        f16x8 m4 = pack8(wi4[8]+wh4[8],   wi4[9]+wh4[9]);
        f16x8 m5 = pack8(wi4[10]+wh4[10], wi4[11]+wh4[11]);
        f16x8 m6 = pack8(wi4[12]+wh4[12], wi4[13]+wh4[13]);
        f16x8 m7 = pack8(wi4[14]+wh4[14], wi4[15]+wh4[15]);
        PIN8(m0); PIN8(m1); PIN8(m2); PIN8(m3);
        PIN8(m4); PIN8(m5); PIN8(m6); PIN8(m7);

        hl[e] = f2h(tgt[(size_t)b * T_ * E_ + h * D_ + e]);  // k0

        u16* nwp = nwh + (size_t)bid * T_ * D_;
        const f16x8* hl8 = (const f16x8*)hl;

        {
            f16x8 x0=hl8[0],x1=hl8[1],x2=hl8[2],x3=hl8[3],
                  x4=hl8[4],x5=hl8[5],x6=hl8[6],x7=hl8[7];
            float s0=dot8(n0,x0,c),   s1=dot8(n1,x1,0.f),
                  s2=dot8(n2,x2,0.f), s3=dot8(n3,x3,0.f),
                  s4=dot8(n4,x4,0.f), s5=dot8(n5,x5,0.f),
                  s6=dot8(n6,x6,0.f), s7=dot8(n7,x7,0.f);
            float hv = ftanh(((s0+s1)+(s2+s3)) + ((s4+s5)+(s6+s7)));
            u16 hb = f2h(hv);
            hl[e] = hb;
            nwp[e] = hb;
        }

        #pragma unroll 1
        for (int t = 1; t < T_; ++t) {
            f16x8 x0=hl8[0],x1=hl8[1],x2=hl8[2],x3=hl8[3],
                  x4=hl8[4],x5=hl8[5],x6=hl8[6],x7=hl8[7];
            float s0=dot8(m0,x0,c),   s1=dot8(m1,x1,0.f),
                  s2=dot8(m2,x2,0.f), s3=dot8(m3,x3,0.f),
                  s4=dot8(m4,x4,0.f), s5=dot8(m5,x5,0.f),
                  s6=dot8(m6,x6,0.f), s7=dot8(m7,x7,0.f);
            float hv = ftanh(((s0+s1)+(s2+s3)) + ((s4+s5)+(s6+s7)));
            u16 hb = f2h(hv);
            hl[e] = hb;
            nwp[(size_t)t * D_ + e] = hb;
        }
    } else {
        int pb   = bid - BH_;          // 0 .. 4095
        int bh   = pb >> 5;            // (b*16+h)
        int tile = pb & 31;            // 32 t-rows per block
        int b = bh >> 4, h = bh & 15;
        int e  = threadIdx.x & 63;
        int tg = threadIdx.x >> 6;
        int t0 = tile * 32 + tg * 8;

        const float* wq = Wq + (size_t)h * D_ * D_ + e;  // column e, stride 64
        const float* wv = Wv + (size_t)h * D_ * D_ + e;
        const float* s0 = src + ((size_t)b * T_ + t0) * E_ + h * D_;
        const float* g0 = tgt + ((size_t)b * T_ + t0) * E_ + h * D_;

        float aq[8] = {0,0,0,0,0,0,0,0};
        float av[8] = {0,0,0,0,0,0,0,0};
        #pragma unroll 4
        for (int d4 = 0; d4 < 16; ++d4) {
            float q0 = wq[(4*d4+0)*64], q1 = wq[(4*d4+1)*64],
                  q2 = wq[(4*d4+2)*64], q3 = wq[(4*d4+3)*64];
            float v0 = wv[(4*d4+0)*64], v1 = wv[(4*d4+1)*64],
                  v2 = wv[(4*d4+2)*64], v3 = wv[(4*d4+3)*64];
            #pragma unroll
            for (int j = 0; j < 8; ++j) {
                float4 x = *(const float4*)(s0 + (size_t)j * E_ + 4*d4);
                float4 y = *(const float4*)(g0 + (size_t)j * E_ + 4*d4);
                aq[j] += x.x*q0 + x.y*q1 + x.z*q2 + x.w*q3;
                av[j] += y.x*v0 + y.y*v1 + y.z*v2 + y.w*v3;
            }
        }
        u16* qp = qh + ((size_t)bh * T_ + t0) * D_ + e;
        #pragma unroll
        for (int j = 0; j < 8; ++j) qp[(size_t)j * D_] = f2h(aq[j] * (1.0f/256.0f));
        f16x8 vv;
        #pragma unroll
        for (int j = 0; j < 8; ++j) vv[j] = (f16)av[j];
        *(f16x8*)(vh + ((size_t)bh * D_ + e) * T_ + t0) = vv;
    }
}

// ---------------------------------------------------------------------------
// Kernel 2: flash attention, f16 MFMA 16x16x32 (HW-verified layouts from the
// round-0 kernel), restructured for amortization:
//  - block = 128 q-rows (4 waves x 2 groups of 16): K-frag reads, V-frag
//    reads, K/V staging and barriers shared across both groups.
//  - deferred denominator: lane-local partial sums per kt, ONE 16-lane
//    shfl reduce after the loop (was 16 shuffles per kt per wave).
//  - rcp epilogue.
// Layouts, swizzles, MFMA operand patterns byte-identical to round 0.
// ---------------------------------------------------------------------------
#define MFMA16(a, b, c) __builtin_amdgcn_mfma_f32_16x16x32_f16(a, b, c, 0, 0, 0)

__global__ __launch_bounds__(256) void attn_kernel(
    const u16* __restrict__ qh,   // [bh][t][64] f16, pre-scaled 1/256
    const u16* __restrict__ kh,   // nw states [bh][t][64] f16
    const u16* __restrict__ vh,   // V^T [bh][d][t] f16
    const float* __restrict__ Wo, // [H][64][64] fp32
    float* __restrict__ out)      // [B][T][E] fp32
{
    __shared__ __align__(16) u16 Klds[64 * 64];        // keys; later Wo^T
    __shared__ __align__(16) u16 Vlds[64 * 64];        // V^T: row=d, col=key
    __shared__ __align__(16) u16 Plds[4][2][16 * 64];  // per-wave per-group P/O

    const int tid  = threadIdx.x;
    const int lane = tid & 63;
    const int w    = tid >> 6;
    const int l15  = lane & 15;
    const int quad = lane >> 4;
    const int sw   = lane & 7;
    const int bh   = blockIdx.y;
    const int qt   = blockIdx.x;

    const size_t base  = (size_t)bh * T_ * D_;
    const size_t vbase = (size_t)bh * D_ * T_;

    // Q fragments for both 16-row groups (rows16 index = w + 4g)
    f16x8 aq[2][2];
    #pragma unroll
    for (int g = 0; g < 2; ++g) {
        int qrow = qt * 128 + (w + 4 * g) * 16 + l15;
        const f16x8* qp = (const f16x8*)(qh + base + (size_t)qrow * 64 + quad * 8);
        aq[g][0] = qp[0];
        aq[g][1] = qp[4];
    }

    f32x4 oacc[2][4];
    float lrun[2][4];
    #pragma unroll
    for (int g = 0; g < 2; ++g)
        #pragma unroll
        for (int i = 0; i < 4; ++i) {
            oacc[g][i] = (f32x4){0.f, 0.f, 0.f, 0.f};
            lrun[g][i] = 0.f;
        }

    #pragma unroll 1
    for (int kt = 0; kt < 16; ++kt) {
        // ---- stage K rows + V^T rows, vectorized b128, swizzled ----
        #pragma unroll
        for (int i = 0; i < 2; ++i) {
            int ch = tid + 256 * i;          // 512 chunks of 8 u16
            int r = ch >> 3, cc = ch & 7;
            short8 kval = *(const short8*)(kh + base + (size_t)(kt * 64 + r) * 64 + cc * 8);
            *(short8*)&Klds[r * 64 + ((cc ^ (r & 7)) * 8)] = kval;
            short8 vval = *(const short8*)(vh + vbase + (size_t)r * T_ + kt * 64 + cc * 8);
            *(short8*)&Vlds[r * 64 + ((cc ^ (r & 7)) * 8)] = vval;
        }
        __syncthreads();

        // ---- S = Q K^T, K-fragments shared across both q-groups ----
        f32x4 sacc[2][4];
        #pragma unroll
        for (int u = 0; u < 4; ++u) {
            int row = 16 * u + l15;
            f16x8 bk0 = *(const f16x8*)&Klds[row * 64 + (((quad + 0) ^ sw) * 8)];
            f16x8 bk1 = *(const f16x8*)&Klds[row * 64 + (((quad + 4) ^ sw) * 8)];
            #pragma unroll
            for (int g = 0; g < 2; ++g) {
                f32x4 z = (f32x4){0.f, 0.f, 0.f, 0.f};
                z = MFMA16(aq[g][0], bk0, z);
                z = MFMA16(aq[g][1], bk1, z);
                sacc[g][u] = z;
            }
        }

        // ---- softmax: exp + lane-local partial sums (reduce deferred) ----
        #pragma unroll
        for (int g = 0; g < 2; ++g) {
            float pr[4][4];
            #pragma unroll
            for (int r = 0; r < 4; ++r) {
                float rs = 0.f;
                #pragma unroll
                for (int u = 0; u < 4; ++u) {
                    float pv = __expf(sacc[g][u][r]);
                    pr[u][r] = pv;
                    rs += pv;
                }
                lrun[g][r] += rs;
            }
            // P -> per-wave per-group LDS (C-layout -> A-fragment layout)
            u16* Pw = Plds[w][g];
            #pragma unroll
            for (int u = 0; u < 4; ++u) {
                int col = 16 * u + l15;
                #pragma unroll
                for (int r = 0; r < 4; ++r) {
                    int row = quad * 4 + r;
                    Pw[row * 64 + (((col >> 3) ^ (row & 7)) * 8) + (col & 7)] = f2h(pr[u][r]);
                }
            }
        }

        // ---- O += P V, V-fragments shared across both q-groups ----
        #pragma unroll
        for (int kc = 0; kc < 2; ++kc) {
            int csel = ((quad + 4 * kc) ^ sw) * 8;
            f16x8 ap0 = *(const f16x8*)&Plds[w][0][l15 * 64 + csel];
            f16x8 ap1 = *(const f16x8*)&Plds[w][1][l15 * 64 + csel];
            #pragma unroll
            for (int nt = 0; nt < 4; ++nt) {
                f16x8 bv = *(const f16x8*)&Vlds[(16 * nt + l15) * 64 + csel];
                oacc[0][nt] = MFMA16(ap0, bv, oacc[0][nt]);
                oacc[1][nt] = MFMA16(ap1, bv, oacc[1][nt]);
            }
        }
        __syncthreads();
    }

    // ---- deferred denominator: one 16-lane reduce per (g, r) ----
    float inv[2][4];
    #pragma unroll
    for (int g = 0; g < 2; ++g)
        #pragma unroll
        for (int r = 0; r < 4; ++r) {
            float s = lrun[g][r];
            #pragma unroll
            for (int off = 1; off < 16; off <<= 1)
                s += __shfl_xor(s, off, 16);
            inv[g][r] = __builtin_amdgcn_rcpf(s);
        }

    // ---- fused output projection: out_tile = (O/l) * Wo[h] ----
    const int b  = bh >> 4, hh = bh & 15;
    {
        const float* wo = Wo + (size_t)hh * D_ * D_;
        #pragma unroll
        for (int i = 0; i < 2; ++i) {
            int ch = tid + 256 * i;          // e = ch>>3, dc = ch&7
            int e = ch >> 3, dc = ch & 7;
            short8 vch;
            #pragma unroll
            for (int j = 0; j < 8; ++j)
                vch[j] = (short)f2h(wo[(size_t)(dc * 8 + j) * D_ + e]);
            *(short8*)&Klds[e * 64 + ((dc ^ (e & 7)) * 8)] = vch;
        }
    }
    #pragma unroll
    for (int g = 0; g < 2; ++g) {
        u16* Pw = Plds[w][g];
        #pragma unroll
        for (int nt = 0; nt < 4; ++nt) {
            int col = 16 * nt + l15;             // d
            #pragma unroll
            for (int r = 0; r < 4; ++r) {
                int row = quad * 4 + r;          // q
                Pw[row * 64 + (((col >> 3) ^ (row & 7)) * 8) + (col & 7)] =
                    f2h(oacc[g][nt][r] * inv[g][r]);
            }
        }
    }
    __syncthreads();    // Wo^T staging + O relayout visible

    f16x8 ao[2][2];
    #pragma unroll
    for (int g = 0; g < 2; ++g) {
        ao[g][0] = *(const f16x8*)&Plds[w][g][l15 * 64 + (((quad + 0) ^ sw) * 8)];
        ao[g][1] = *(const f16x8*)&Plds[w][g][l15 * 64 + (((quad + 4) ^ sw) * 8)];
    }
    f32x4 oo[2][4];
    #pragma unroll
    for (int g = 0; g < 2; ++g)
        #pragma unroll
        for (int nt = 0; nt < 4; ++nt)
            oo[g][nt] = (f32x4){0.f, 0.f, 0.f, 0.f};
    #pragma unroll
    for (int nt = 0; nt < 4; ++nt) {
        int erow = 16 * nt + l15;
        f16x8 b0 = *(const f16x8*)&Klds[erow * 64 + (((quad + 0) ^ (erow & 7)) * 8)];
        f16x8 b1 = *(const f16x8*)&Klds[erow * 64 + (((quad + 4) ^ (erow & 7)) * 8)];
        #pragma unroll
        for (int g = 0; g < 2; ++g) {
            oo[g][nt] = MFMA16(ao[g][0], b0, oo[g][nt]);
            oo[g][nt] = MFMA16(ao[g][1], b1, oo[g][nt]);
        }
    }
    #pragma unroll
    for (int g = 0; g < 2; ++g)
        #pragma unroll
        for (int nt = 0; nt < 4; ++nt)
            #pragma unroll
            for (int r = 0; r < 4; ++r) {
                int qg = qt * 128 + (w + 4 * g) * 16 + quad * 4 + r;
                int e  = 16 * nt + l15;
                out[((size_t)b * T_ + qg) * E_ + hh * D_ + e] = oo[g][nt][r];
            }
}

// ---------------------------------------------------------------------------
extern "C" void kernel_launch(void* const* d_in, const int* in_sizes, int n_in,
                              void* d_out, int out_size, void* d_ws, size_t ws_size,
                              hipStream_t stream)
{
    const float* src = (const float*)d_in[0];
    const float* tgt = (const float*)d_in[1];
    const float* Wq  = (const float*)d_in[2];
    const float* Wv  = (const float*)d_in[3];
    const float* Wo  = (const float*)d_in[4];
    const float* Wih = (const float*)d_in[5];
    const float* Whh = (const float*)d_in[6];
    const float* bih = (const float*)d_in[7];
    const float* bhh = (const float*)d_in[8];
    float* out = (float*)d_out;

    char* ws = (char*)d_ws;
    u16* qh  = (u16*)(ws);                             // [bh][t][d] 16 MB
    u16* vh  = (u16*)(ws + (size_t)16 * 1024 * 1024);  // V^T [bh][d][t] 16 MB
    u16* nwh = (u16*)(ws + (size_t)32 * 1024 * 1024);  // [bh][t][d] 16 MB

    (void)in_sizes; (void)n_in; (void)out_size; (void)ws_size;

    proj_rnn_kernel<<<dim3(BH_ + 4096), 256, 0, stream>>>(
        src, tgt, Wq, Wv, Wih, Whh, bih, bhh, qh, vh, nwh);
    attn_kernel<<<dim3(8, BH_), 256, 0, stream>>>(qh, nwh, vh, Wo, out);
}